// Round 4
// baseline (188.302 us; speedup 1.0000x reference)
//
#include <hip/hip_runtime.h>
#include <cstdint>

// ---------------- problem constants ----------------
#define H_IN   128
#define W_IN   128
#define C_IN   256
#define O_OUT  256
#define OH     126
#define OW     126

// ---------------- tiling ----------------
#define TY     16               // output tile height
#define TX     8                // output tile width (2 px per lane, x-paired)
#define IR     (TY + 2)         // 18 input rows staged
#define ICOL   (TX + 2)         // 10 input cols staged
#define RSD    6                // row stride in dwords (12 bf16: 10 real + 2 pad)
#define CHD    109              // channel stride in dwords (18*6=108 +1 -> odd: write perm)
#define PASS_CH 128             // channels per staging pass (2 passes)
#define IN_DW  (PASS_CH * CHD)  // 13952 dwords = 55808 B
#define LDS_BYTES (IN_DW * 4)   // 55808 B -> 2 blocks/CU
#define NWAVES 8
#define OPW    32               // output channels per wave
#define SST    17               // flush-stage dword stride (odd -> perm banks)

// ---------------- prep: bucket entries by (o, c-half, j-parity) ----------------
// weight_indices [nnz,4]; dtype int32 (JAX default) or int64 — runtime-detected.
__global__ void prep_kernel(const int* __restrict__ wi, const float* __restrict__ wv,
                            int nnz, int* __restrict__ offs, int2* __restrict__ entries) {
    __shared__ int cnt[1024];
    __shared__ int ssum[256];
    __shared__ int is32;
    const int tid = threadIdx.x;
    for (int k = tid; k < 1024; k += 256) cnt[k] = 0;
    if (tid == 0) is32 = 0;
    __syncthreads();
    int f = 0;
    for (int idx = tid * 2 + 1; idx < nnz * 4; idx += 512) f |= wi[idx];
    if (f) atomicOr(&is32, 1);
    __syncthreads();
    const int stride = is32 ? 4 : 8;
    const int step   = is32 ? 1 : 2;
    for (int e = tid; e < nnz; e += 256) {
        int o  = wi[e * stride];
        int h  = wi[e * stride + 1 * step];
        int w_ = wi[e * stride + 2 * step];
        int c  = wi[e * stride + 3 * step];
        int k   = h * 768 + w_ * 256 + c;      // faithful (kh,kw,C)->(C,kh,kw) scramble
        int cp  = k / 9;
        int rem = k - cp * 9;
        int i_  = rem / 3;
        int j_  = rem - i_ * 3;
        int bucket = o * 4 + (cp >> 7) * 2 + (j_ == 1);
        atomicAdd(&cnt[bucket], 1);
    }
    __syncthreads();
    int local = cnt[4 * tid] + cnt[4 * tid + 1] + cnt[4 * tid + 2] + cnt[4 * tid + 3];
    ssum[tid] = local;
    __syncthreads();
    for (int d = 1; d < 256; d <<= 1) {        // Hillis-Steele inclusive scan
        int v = (tid >= d) ? ssum[tid - d] : 0;
        __syncthreads();
        ssum[tid] += v;
        __syncthreads();
    }
    int run = ssum[tid] - local;               // exclusive prefix
    for (int k = 0; k < 4; ++k) {
        int c_ = cnt[4 * tid + k];
        offs[4 * tid + k] = run;
        cnt[4 * tid + k] = run;                // scatter cursor
        run += c_;
    }
    if (tid == 255) offs[1024] = ssum[255];
    __syncthreads();
    for (int e = tid; e < nnz; e += 256) {
        int o  = wi[e * stride];
        int h  = wi[e * stride + 1 * step];
        int w_ = wi[e * stride + 2 * step];
        int c  = wi[e * stride + 3 * step];
        int k   = h * 768 + w_ * 256 + c;
        int cp  = k / 9;
        int rem = k - cp * 9;
        int i_  = rem / 3;
        int j_  = rem - i_ * 3;
        int c_loc = cp & 127;
        int meta  = c_loc * CHD + i_ * RSD + (j_ >> 1);  // LDS dword delta
        int bucket = o * 4 + (cp >> 7) * 2 + (j_ == 1);
        int pos = atomicAdd(&cnt[bucket], 1);
        entries[pos] = make_int2(meta, __float_as_int(wv[e]));
    }
}

// round-to-nearest-even fp32 -> bf16 bits
__device__ inline unsigned rtne_bf16(float f) {
    unsigned u = __float_as_uint(f);
    u += 0x7FFFu + ((u >> 16) & 1u);
    return u >> 16;
}

typedef float f2 __attribute__((ext_vector_type(2)));

// ---------------- main conv kernel ----------------
__global__ __launch_bounds__(512, 4)
void conv_kernel(const float* __restrict__ in, float* __restrict__ out,
                 const int* __restrict__ offs, const int2* __restrict__ E) {
    extern __shared__ char smem[];
    unsigned* ldsU = (unsigned*)smem;
    float*    ldsF = (float*)smem;

    const int tid  = threadIdx.x;
    const int w    = tid >> 6;
    const int lane = tid & 63;
    const int bx = blockIdx.x, by = blockIdx.y, b = blockIdx.z;
    const int ix0 = bx * TX, iy0 = by * TY;
    const float* inb = in + (size_t)b * (H_IN * W_IN * C_IN);

    const int ly = lane >> 2, lx = lane & 3;
    const int A  = ly * RSD + lx;          // lane base: bank=(6ly+lx)%32 -> 2-way uniform
    const int ob = w * OPW;

    f2 acc[OPW];
#pragma unroll
    for (int k = 0; k < OPW; ++k) acc[k] = (f2)0.f;

    for (int pass = 0; pass < 2; ++pass) {
        if (pass) __syncthreads();   // all gathers of prev pass done before restage
        // ---- stage 128 channels, channel-major bf16, x-paired dwords ----
        // unit u: ch-half (0/1), row r (0..17), x-quad xq (0..4)
        for (int u = w; u < 2 * IR * 5; u += NWAVES) {
            int ch = u >= IR * 5;
            int px = u - ch * IR * 5;
            int r  = px / 5, xq = px - r * 5;
            int gy = iy0 + r, gx = ix0 + 2 * xq;
            int cg = pass * PASS_CH + ch * 64 + lane;
            float f0 = 0.f, f1 = 0.f;
            if (gy < H_IN) {                       // wave-uniform guards
                const float* pp = inb + ((gy * W_IN + gx) << 8) + cg;
                if (gx < W_IN)     f0 = pp[0];
                if (gx + 1 < W_IN) f1 = pp[C_IN];
            }
            unsigned pk = rtne_bf16(f0) | (rtne_bf16(f1) << 16);
            ldsU[(ch * 64 + lane) * CHD + r * RSD + xq] = pk;   // bank perm (CHD odd)
        }
        __syncthreads();

        // ---- gather: lane = x-pair of pixels; wave owns 32 output channels ----
#pragma unroll
        for (int oi = 0; oi < OPW; ++oi) {
            const int base = (ob + oi) * 4 + pass * 2;
            const int g0 = offs[base], g1 = offs[base + 1], g2 = offs[base + 2];
            f2 a = acc[oi];
            for (int t = g0; t < g1; ++t) {        // j even: one ds_read_b32
                int2 q = E[t];
                unsigned d = ldsU[A + q.x];
                f2 x;
                x.x = __uint_as_float(d << 16);
                x.y = __uint_as_float(d & 0xFFFF0000u);
                float wv = __int_as_float(q.y);
                a.x += wv * x.x;
                a.y += wv * x.y;
            }
            for (int t = g1; t < g2; ++t) {        // j==1: ds_read2_b32 + alignbit
                int2 q = E[t];
                int idx = A + q.x;
                unsigned d0 = ldsU[idx], d1 = ldsU[idx + 1];
                unsigned d  = __builtin_amdgcn_alignbit(d1, d0, 16);
                f2 x;
                x.x = __uint_as_float(d << 16);
                x.y = __uint_as_float(d & 0xFFFF0000u);
                float wv = __int_as_float(q.y);
                a.x += wv * x.x;
                a.y += wv * x.y;
            }
            acc[oi] = a;
        }
    }

    // ---- flush: reuse input LDS region; 4 rounds (x-half h, ch-half q) ----
    __syncthreads();
    float* stg = ldsF + w * (64 * SST);
    const float* rb = stg;
    for (int h = 0; h < 2; ++h) {
        for (int q = 0; q < 2; ++q) {
            float* sl = stg + lane * SST;
#pragma unroll
            for (int k = 0; k < 16; ++k)
                sl[k] = h ? acc[q * 16 + k].y : acc[q * 16 + k].x;
            __syncthreads();
            const int chp = lane >> 4;      // 0..3
            const int chc = lane & 15;      // 0..15
#pragma unroll
            for (int st = 0; st < 16; ++st) {
                int p = st * 4 + chp;       // p = ly*4 + lx of producing lane
                float v = rb[p * SST + chc];
                int oy = iy0 + (p >> 2);
                int ox = ix0 + 2 * (p & 3) + h;
                if (oy < OH && ox < OW)
                    out[(((size_t)b * OH + oy) * OW + ox) * O_OUT + ob + q * 16 + chc] = v;
            }
            __syncthreads();
        }
    }
}

// ---------------- host ----------------
extern "C" void kernel_launch(void* const* d_in, const int* in_sizes, int n_in,
                              void* d_out, int out_size, void* d_ws, size_t ws_size,
                              hipStream_t stream) {
    const float* input = (const float*)d_in[0];
    const int*   widx  = (const int*)d_in[1];    // int32 or int64 (runtime-detected)
    const float* wval  = (const float*)d_in[2];
    float* outp = (float*)d_out;
    const int nnz = in_sizes[2];
    const int B = in_sizes[0] / (H_IN * W_IN * C_IN);

    int*  offs    = (int*)d_ws;                          // 1025 ints
    int2* entries = (int2*)((char*)d_ws + 4104);         // 8B-aligned

    prep_kernel<<<1, 256, 0, stream>>>(widx, wval, nnz, offs, entries);

    static_assert(NWAVES * 64 * SST <= IN_DW, "flush stage must fit in input region");
    static_assert(LDS_BYTES <= 80 * 1024, "need 2 blocks/CU");
    hipFuncSetAttribute((const void*)conv_kernel,
                        hipFuncAttributeMaxDynamicSharedMemorySize, LDS_BYTES);
    dim3 grid((OW + TX - 1) / TX, (OH + TY - 1) / TY, B);
    conv_kernel<<<grid, 512, LDS_BYTES, stream>>>(input, outp, offs, entries);
}